// Round 1
// baseline (798.002 us; speedup 1.0000x reference)
//
#include <hip/hip_runtime.h>
#include <hip/hip_bf16.h>
#include <math.h>

#define N 4096
#define C 256
#define KSEL 20
#define ROWS 4

// ---------------------------------------------------------------------------
// Kernel 1: inverse row norms.  rinv[row] = 1 / max(||X[row]||, 1e-12)
// ---------------------------------------------------------------------------
__global__ __launch_bounds__(256) void rinv_kernel(const float* __restrict__ X,
                                                   float* __restrict__ rinv) {
    const int row = blockIdx.x;
    const int tid = threadIdx.x;
    float v = X[(size_t)row * C + tid];
    float s = v * v;
#pragma unroll
    for (int off = 32; off; off >>= 1) s += __shfl_xor(s, off, 64);
    __shared__ float p[4];
    if ((tid & 63) == 0) p[tid >> 6] = s;
    __syncthreads();
    if (tid == 0) {
        float t = p[0] + p[1] + p[2] + p[3];
        rinv[row] = 1.0f / fmaxf(sqrtf(t), 1e-12f);
    }
}

// ---------------------------------------------------------------------------
// Kernel 2: per-block ROWS rows. Compute full dist row(s) into registers,
// then iterative top-K min/max extraction per row.
// Thread tid owns dist values for j = jt*256 + tid, jt = 0..15.
// ---------------------------------------------------------------------------
__global__ __launch_bounds__(256) void dist_topk_kernel(
    const float* __restrict__ A, const float* __restrict__ B,
    const float* __restrict__ rinva, const float* __restrict__ rinvb,
    float* __restrict__ loss) {
    const int tid  = threadIdx.x;
    const int lane = tid & 63;
    const int wid  = tid >> 6;
    const int row0 = blockIdx.x * ROWS;

    __shared__ __align__(16) float a_s[ROWS][C];
    __shared__ float redv[4];
    __shared__ int   redi[4];
    __shared__ float bc_v;
    __shared__ int   bc_i;

#pragma unroll
    for (int r = 0; r < ROWS; ++r)
        a_s[r][tid] = A[(size_t)(row0 + r) * C + tid] * rinva[row0 + r];
    __syncthreads();

    // ---- distance computation: d[r][jt] = dist[row0+r][jt*256+tid] ----
    float d[ROWS][N / 256];
#pragma unroll
    for (int jt = 0; jt < N / 256; ++jt) {
        const int j = jt * 256 + tid;
        const float4* __restrict__ b4 = (const float4*)(B + (size_t)j * C);
        float acc[ROWS];
#pragma unroll
        for (int r = 0; r < ROWS; ++r) acc[r] = 0.f;
#pragma unroll 8
        for (int c = 0; c < C / 4; ++c) {
            float4 b = b4[c];
#pragma unroll
            for (int r = 0; r < ROWS; ++r) {
                float4 x = ((const float4*)a_s[r])[c];
                acc[r] += x.x * b.x + x.y * b.y + x.z * b.z + x.w * b.w;
            }
        }
        const float rb = rinvb[j];
#pragma unroll
        for (int r = 0; r < ROWS; ++r)
            d[r][jt] = (1.0f - acc[r] * rb) * 0.5f;
    }

    // ---- per-row top-K min + top-K max ----
#pragma unroll
    for (int r = 0; r < ROWS; ++r) {
        const int grow  = row0 + r;
        const int dslot = grow >> 8;   // block-uniform
        const int downr = grow & 255;  // owner thread of the diagonal

        // broadcast diagonal value (dist_ap)
        if (tid == downr) {
#pragma unroll
            for (int k = 0; k < N / 256; ++k)
                if (k == dslot) bc_v = d[r][k];
        }
        __syncthreads();
        const float dap = bc_v;

        float total = 0.f;  // meaningful on thread 0 only

        // ================= MIN pass =================
        {
            float w[N / 256];
#pragma unroll
            for (int k = 0; k < N / 256; ++k) w[k] = d[r][k];
            if (tid == downr) {
#pragma unroll
                for (int k = 0; k < N / 256; ++k)
                    if (k == dslot) w[k] = __builtin_inff();
            }
            for (int it = 0; it < KSEL; ++it) {
                float bv = __builtin_inff();
                int   bi = 0;
#pragma unroll
                for (int k = 0; k < N / 256; ++k) {
                    const int j = k * 256 + tid;
                    if (w[k] < bv) { bv = w[k]; bi = j; }
                }
#pragma unroll
                for (int off = 32; off; off >>= 1) {
                    float ov = __shfl_xor(bv, off, 64);
                    int   oi = __shfl_xor(bi, off, 64);
                    if (ov < bv) { bv = ov; bi = oi; }
                }
                if (lane == 0) { redv[wid] = bv; redi[wid] = bi; }
                __syncthreads();
                if (tid == 0) {
                    float mv = redv[0]; int mi = redi[0];
#pragma unroll
                    for (int x = 1; x < 4; ++x)
                        if (redv[x] < mv) { mv = redv[x]; mi = redi[x]; }
                    total += mv;
                    bc_i = mi;
                }
                __syncthreads();
                const int mi = bc_i;
                if (tid == (mi & 255)) {
                    const int slot = mi >> 8;
#pragma unroll
                    for (int k = 0; k < N / 256; ++k)
                        if (k == slot) w[k] = __builtin_inff();
                }
            }
        }

        // ================= MAX pass =================
        {
            float w[N / 256];
#pragma unroll
            for (int k = 0; k < N / 256; ++k) w[k] = d[r][k];
            if (tid == downr) {
#pragma unroll
                for (int k = 0; k < N / 256; ++k)
                    if (k == dslot) w[k] = -__builtin_inff();
            }
            for (int it = 0; it < KSEL; ++it) {
                float bv = -__builtin_inff();
                int   bi = 0;
#pragma unroll
                for (int k = 0; k < N / 256; ++k) {
                    const int j = k * 256 + tid;
                    if (w[k] > bv) { bv = w[k]; bi = j; }
                }
#pragma unroll
                for (int off = 32; off; off >>= 1) {
                    float ov = __shfl_xor(bv, off, 64);
                    int   oi = __shfl_xor(bi, off, 64);
                    if (ov > bv) { bv = ov; bi = oi; }
                }
                if (lane == 0) { redv[wid] = bv; redi[wid] = bi; }
                __syncthreads();
                if (tid == 0) {
                    float mv = redv[0]; int mi = redi[0];
#pragma unroll
                    for (int x = 1; x < 4; ++x)
                        if (redv[x] > mv) { mv = redv[x]; mi = redi[x]; }
                    total += mv;
                    bc_i = mi;
                }
                __syncthreads();
                const int mi = bc_i;
                if (tid == (mi & 255)) {
                    const int slot = mi >> 8;
#pragma unroll
                    for (int k = 0; k < N / 256; ++k)
                        if (k == slot) w[k] = -__builtin_inff();
                }
            }
        }

        if (tid == 0) {
            const float neg = -0.0125f * total;   // -((1-prior)/(1*2K)) * sum
            const float pos = 0.5f * dap;         // (prior/1) * dist_ap
            loss[grow] = (neg < 0.f) ? -neg : (pos + neg);
        }
        __syncthreads();  // protect bc_v/bc_i for next row
    }
}

// ---------------------------------------------------------------------------
// Kernel 3: deterministic mean of loss[0..N-1] -> out[0]
// ---------------------------------------------------------------------------
__global__ __launch_bounds__(256) void finalize_kernel(const float* __restrict__ loss,
                                                       float* __restrict__ out) {
    const int tid = threadIdx.x;
    float s = 0.f;
    for (int k = tid; k < N; k += 256) s += loss[k];
#pragma unroll
    for (int off = 32; off; off >>= 1) s += __shfl_xor(s, off, 64);
    __shared__ float p[4];
    if ((tid & 63) == 0) p[tid >> 6] = s;
    __syncthreads();
    if (tid == 0) out[0] = (p[0] + p[1] + p[2] + p[3]) * (1.0f / (float)N);
}

// ---------------------------------------------------------------------------
extern "C" void kernel_launch(void* const* d_in, const int* in_sizes, int n_in,
                              void* d_out, int out_size, void* d_ws, size_t ws_size,
                              hipStream_t stream) {
    const float* A = (const float*)d_in[0];  // input  [N,C] f32
    const float* B = (const float*)d_in[1];  // target [N,C] f32
    float* ws    = (float*)d_ws;
    float* rinva = ws;
    float* rinvb = ws + N;
    float* lossv = ws + 2 * N;

    rinv_kernel<<<N, 256, 0, stream>>>(A, rinva);
    rinv_kernel<<<N, 256, 0, stream>>>(B, rinvb);
    dist_topk_kernel<<<N / ROWS, 256, 0, stream>>>(A, B, rinva, rinvb, lossv);
    finalize_kernel<<<1, 256, 0, stream>>>(lossv, (float*)d_out);
}

// Round 2
// 544.799 us; speedup vs baseline: 1.4648x; 1.4648x over previous
//
#include <hip/hip_runtime.h>
#include <hip/hip_bf16.h>
#include <math.h>

#define N 4096
#define C 256
#define KSEL 20
#define ROWS 4
#define JT (N / 256)   // j-tiles per thread

// monotone key: dist clamped to [0,1], +1.0 -> bits in [0x3F800000, 0x40000000]
__device__ __forceinline__ unsigned key_of(float d) {
    return __float_as_uint(fminf(fmaxf(d, 0.0f), 1.0f) + 1.0f);
}

// ---------------------------------------------------------------------------
// Kernel 1: inverse row norms.  rinv[row] = 1 / max(||X[row]||, 1e-12)
// ---------------------------------------------------------------------------
__global__ __launch_bounds__(256) void rinv_kernel(const float* __restrict__ X,
                                                   float* __restrict__ rinv) {
    const int row = blockIdx.x;
    const int tid = threadIdx.x;
    float v = X[(size_t)row * C + tid];
    float s = v * v;
#pragma unroll
    for (int off = 32; off; off >>= 1) s += __shfl_xor(s, off, 64);
    __shared__ float p[4];
    if ((tid & 63) == 0) p[tid >> 6] = s;
    __syncthreads();
    if (tid == 0) {
        float t = p[0] + p[1] + p[2] + p[3];
        rinv[row] = 1.0f / fmaxf(sqrtf(t), 1e-12f);
    }
}

// ---------------------------------------------------------------------------
// Kernel 2: GEMM (thread tid owns columns j = jt*256+tid) -> LDS transpose so
// wave w owns full row row0+w -> barrier-free count-based top-K per wave.
// ---------------------------------------------------------------------------
__global__ __launch_bounds__(256) void dist_topk_kernel(
    const float* __restrict__ A, const float* __restrict__ B,
    const float* __restrict__ rinva, const float* __restrict__ rinvb,
    float* __restrict__ loss) {
    const int tid  = threadIdx.x;
    const int lane = tid & 63;
    const int wid  = tid >> 6;
    const int row0 = blockIdx.x * ROWS;

    __shared__ __align__(16) float a_s[ROWS][C];   // 4 KB
    __shared__ float dbuf[2][N];                   // 32 KB ping-pong row pair

#pragma unroll
    for (int r = 0; r < ROWS; ++r)
        a_s[r][tid] = A[(size_t)(row0 + r) * C + tid] * rinva[row0 + r];
    __syncthreads();

    // ---- distance computation: d[r][jt] = dist[row0+r][jt*256+tid] ----
    float d[ROWS][JT];
#pragma unroll
    for (int jt = 0; jt < JT; ++jt) {
        const int j = jt * 256 + tid;
        const float4* __restrict__ b4 = (const float4*)(B + (size_t)j * C);
        float acc[ROWS];
#pragma unroll
        for (int r = 0; r < ROWS; ++r) acc[r] = 0.f;
#pragma unroll 8
        for (int c = 0; c < C / 4; ++c) {
            float4 b = b4[c];
#pragma unroll
            for (int r = 0; r < ROWS; ++r) {
                float4 x = ((const float4*)a_s[r])[c];
                acc[r] += x.x * b.x + x.y * b.y + x.z * b.z + x.w * b.w;
            }
        }
        const float rb = rinvb[j];
#pragma unroll
        for (int r = 0; r < ROWS; ++r)
            d[r][jt] = (1.0f - acc[r] * rb) * 0.5f;
    }

    // ---- transpose through LDS: wave w ends up with full row row0+w as keys ----
    unsigned u[64];          // u[k] = key of dist[row0+wid][k*64+lane]
#pragma unroll
    for (int p = 0; p < 2; ++p) {
#pragma unroll
        for (int jt = 0; jt < JT; ++jt) {
            dbuf[0][jt * 256 + tid] = d[2 * p][jt];
            dbuf[1][jt * 256 + tid] = d[2 * p + 1][jt];
        }
        __syncthreads();
        if ((wid >> 1) == p) {
            const int sub = wid & 1;
#pragma unroll
            for (int k = 0; k < 64; ++k)
                u[k] = key_of(dbuf[sub][k * 64 + lane]);
        }
        __syncthreads();
    }

    // ---- per-wave selection (no barriers from here on) ----
    const int grow  = row0 + wid;
    const int dslot = grow >> 6;   // wave-uniform
    const int dlane = grow & 63;

    unsigned dvu = 0;
#pragma unroll
    for (int k = 0; k < 64; ++k)
        if (k == dslot) dvu = u[k];
    const unsigned dku = (unsigned)__shfl((int)dvu, dlane, 64);
    const float dap = __uint_as_float(dku) - 1.0f;

    // key range (diag included: only widens the search interval, counts adjust)
    unsigned kmin = 0xFFFFFFFFu, kmax = 0u;
#pragma unroll
    for (int k = 0; k < 64; ++k) {
        kmin = min(kmin, u[k]);
        kmax = max(kmax, u[k]);
    }
#pragma unroll
    for (int off = 32; off; off >>= 1) {
        kmin = min(kmin, (unsigned)__shfl_xor((int)kmin, off, 64));
        kmax = max(kmax, (unsigned)__shfl_xor((int)kmax, off, 64));
    }

    // ====== 20th SMALLEST: find T with cnt(<T) < K <= cnt(<=T) ======
    unsigned lo = kmin, hi = kmax + 1;
    int clo = 0;
    while (hi - lo > 1u) {
        const unsigned mid = lo + ((hi - lo) >> 1);
        int c = 0;
#pragma unroll
        for (int k = 0; k < 64; ++k)
            c += (int)__popcll(__ballot(u[k] < mid));
        c -= (dku < mid) ? 1 : 0;   // exclude diagonal
        if (c < KSEL) { lo = mid; clo = c; } else hi = mid;
    }
    const unsigned Tmin = lo;
    float s = 0.f;
#pragma unroll
    for (int k = 0; k < 64; ++k)
        if (u[k] < Tmin) s += __uint_as_float(u[k]) - 1.0f;
#pragma unroll
    for (int off = 32; off; off >>= 1) s += __shfl_xor(s, off, 64);
    const float sum_min = s - ((dku < Tmin) ? dap : 0.f)
                        + (float)(KSEL - clo) * (__uint_as_float(Tmin) - 1.0f);

    // ====== 20th LARGEST: find T with cnt(>T) < K <= cnt(>=T) ======
    lo = kmin - 1; hi = kmax;
    int chi = 0;
    while (hi - lo > 1u) {
        const unsigned mid = lo + ((hi - lo) >> 1);
        int c = 0;
#pragma unroll
        for (int k = 0; k < 64; ++k)
            c += (int)__popcll(__ballot(u[k] > mid));
        c -= (dku > mid) ? 1 : 0;
        if (c < KSEL) { hi = mid; chi = c; } else lo = mid;
    }
    const unsigned Tmax = hi;
    s = 0.f;
#pragma unroll
    for (int k = 0; k < 64; ++k)
        if (u[k] > Tmax) s += __uint_as_float(u[k]) - 1.0f;
#pragma unroll
    for (int off = 32; off; off >>= 1) s += __shfl_xor(s, off, 64);
    const float sum_max = s - ((dku > Tmax) ? dap : 0.f)
                        + (float)(KSEL - chi) * (__uint_as_float(Tmax) - 1.0f);

    if (lane == 0) {
        const float total = sum_min + sum_max;
        const float neg = -0.0125f * total;   // -((1-prior)/(2K)) * sum
        const float pos = 0.5f * dap;         // prior * dist_ap
        loss[grow] = (neg < 0.f) ? -neg : (pos + neg);
    }
}

// ---------------------------------------------------------------------------
// Kernel 3: deterministic mean of loss[0..N-1] -> out[0]
// ---------------------------------------------------------------------------
__global__ __launch_bounds__(256) void finalize_kernel(const float* __restrict__ loss,
                                                       float* __restrict__ out) {
    const int tid = threadIdx.x;
    float s = 0.f;
    for (int k = tid; k < N; k += 256) s += loss[k];
#pragma unroll
    for (int off = 32; off; off >>= 1) s += __shfl_xor(s, off, 64);
    __shared__ float p[4];
    if ((tid & 63) == 0) p[tid >> 6] = s;
    __syncthreads();
    if (tid == 0) out[0] = (p[0] + p[1] + p[2] + p[3]) * (1.0f / (float)N);
}

// ---------------------------------------------------------------------------
extern "C" void kernel_launch(void* const* d_in, const int* in_sizes, int n_in,
                              void* d_out, int out_size, void* d_ws, size_t ws_size,
                              hipStream_t stream) {
    const float* A = (const float*)d_in[0];  // input  [N,C] f32
    const float* B = (const float*)d_in[1];  // target [N,C] f32
    float* ws    = (float*)d_ws;
    float* rinva = ws;
    float* rinvb = ws + N;
    float* lossv = ws + 2 * N;

    rinv_kernel<<<N, 256, 0, stream>>>(A, rinva);
    rinv_kernel<<<N, 256, 0, stream>>>(B, rinvb);
    dist_topk_kernel<<<N / ROWS, 256, 0, stream>>>(A, B, rinva, rinvb, lossv);
    finalize_kernel<<<1, 256, 0, stream>>>(lossv, (float*)d_out);
}

// Round 3
// 98.151 us; speedup vs baseline: 8.1304x; 5.5506x over previous
//
#include <hip/hip_runtime.h>
#include <hip/hip_bf16.h>
#include <math.h>

#define NROW 4096
#define CDIM 256
#define KSEL 20

typedef __attribute__((ext_vector_type(8))) short short8_t;  // 8 bf16 (4 VGPRs)
typedef __attribute__((ext_vector_type(4))) float f32x4;

// ---------------------------------------------------------------------------
// Kernel 1: normalize rows of A and B, store as bf16.
// grid = 2*NROW blocks (first half A, second half B), 256 threads.
// ---------------------------------------------------------------------------
__global__ __launch_bounds__(256) void prep_kernel(const float* __restrict__ A,
                                                   const float* __restrict__ B,
                                                   ushort* __restrict__ An,
                                                   ushort* __restrict__ Bn) {
    const int bid = blockIdx.x;
    const int row = bid & (NROW - 1);
    const float* __restrict__ X = (bid < NROW) ? A : B;
    ushort* __restrict__ Y = (bid < NROW) ? An : Bn;
    const int tid = threadIdx.x;
    float v = X[(size_t)row * CDIM + tid];
    float s = v * v;
#pragma unroll
    for (int off = 32; off; off >>= 1) s += __shfl_xor(s, off, 64);
    __shared__ float p[4];
    __shared__ float rsh;
    if ((tid & 63) == 0) p[tid >> 6] = s;
    __syncthreads();
    if (tid == 0) rsh = 1.0f / fmaxf(sqrtf(p[0] + p[1] + p[2] + p[3]), 1e-12f);
    __syncthreads();
    __hip_bfloat16 h = __float2bfloat16(v * rsh);
    Y[(size_t)row * CDIM + tid] = *(ushort*)&h;
}

// ---------------------------------------------------------------------------
// Kernel 2: bf16 MFMA GEMM dist = (1 - Anorm @ Bnorm^T)*0.5, quantized to u16.
// Block = 128x128 output tile, 4 waves as 2x2, each wave 64x64 (4x4 frags of
// 16x16x32). Operands loaded straight from global (L2/L3) into fragments:
//   A-frag: lane holds A[i0 + (lane&15)][ks*32 + (lane>>4)*8 + e], e=0..7
//   B-frag: lane holds B[j0 + (lane&15)][ks*32 + (lane>>4)*8 + e]  (B^T gemm)
// C/D layout (m89-verified): row = (lane>>4)*4 + reg, col = lane&15.
// dist16 is band-local: rows [r0, r0+band) stored at dist16[(i-r0)*NROW + j].
// ---------------------------------------------------------------------------
__global__ __launch_bounds__(256) void gemm16_kernel(const ushort* __restrict__ An,
                                                     const ushort* __restrict__ Bn,
                                                     ushort* __restrict__ dist16,
                                                     int r0) {
    const int tid  = threadIdx.x;
    const int lane = tid & 63;
    const int wid  = tid >> 6;
    const int wm = wid >> 1, wn = wid & 1;
    const int ib = blockIdx.y * 128 + wm * 64;   // band-local row base
    const int i0 = r0 + ib;                      // global row base
    const int j0 = blockIdx.x * 128 + wn * 64;
    const int lr = lane & 15;
    const int lk = (lane >> 4) * 8;

    f32x4 acc[4][4];
#pragma unroll
    for (int m = 0; m < 4; ++m)
#pragma unroll
        for (int n = 0; n < 4; ++n) acc[m][n] = (f32x4){0.f, 0.f, 0.f, 0.f};

#pragma unroll
    for (int ks = 0; ks < CDIM / 32; ++ks) {
        short8_t a[4], b[4];
#pragma unroll
        for (int m = 0; m < 4; ++m)
            a[m] = *(const short8_t*)(An + (size_t)(i0 + m * 16 + lr) * CDIM + ks * 32 + lk);
#pragma unroll
        for (int n = 0; n < 4; ++n)
            b[n] = *(const short8_t*)(Bn + (size_t)(j0 + n * 16 + lr) * CDIM + ks * 32 + lk);
#pragma unroll
        for (int m = 0; m < 4; ++m)
#pragma unroll
            for (int n = 0; n < 4; ++n)
                acc[m][n] = __builtin_amdgcn_mfma_f32_16x16x32_bf16(a[m], b[n], acc[m][n], 0, 0, 0);
    }

    const int orow = (lane >> 4) * 4;
    const int ocol = lane & 15;
#pragma unroll
    for (int m = 0; m < 4; ++m) {
#pragma unroll
        for (int q = 0; q < 4; ++q) {
            const int irow = ib + m * 16 + orow + q;  // band-local row
#pragma unroll
            for (int n = 0; n < 4; ++n) {
                float d = (1.0f - acc[m][n][q]) * 0.5f;
                d = fminf(fmaxf(d, 0.0f), 1.0f);
                unsigned key = __float2uint_rn(d * 65535.0f);
                dist16[(size_t)irow * NROW + (j0 + n * 16 + ocol)] = (ushort)key;
            }
        }
    }
}

// ---------------------------------------------------------------------------
// Kernel 3: per-row top-K selection on u16 keys. One wave per row.
// Lane l holds keys at columns j = i*512 + l*8 + e (i=0..7, e=0..7):
// loads are 1KB-contiguous per wave-instruction (perfect coalescing).
// Exact integer sums; diagonal excluded via count adjustment.
// ---------------------------------------------------------------------------
__global__ __launch_bounds__(256) void select_kernel(const ushort* __restrict__ dist16,
                                                     float* __restrict__ loss, int r0) {
    const int tid  = threadIdx.x;
    const int lane = tid & 63;
    const int wid  = tid >> 6;
    const int rb   = blockIdx.x * 4 + wid;  // band-local row
    const int grow = r0 + rb;               // global row

    const uint4* __restrict__ P = (const uint4*)(dist16 + (size_t)rb * NROW);
    unsigned u[64];
#pragma unroll
    for (int i = 0; i < 8; ++i) {
        uint4 v = P[i * 64 + lane];
        u[i * 8 + 0] = v.x & 0xFFFFu; u[i * 8 + 1] = v.x >> 16;
        u[i * 8 + 2] = v.y & 0xFFFFu; u[i * 8 + 3] = v.y >> 16;
        u[i * 8 + 4] = v.z & 0xFFFFu; u[i * 8 + 5] = v.z >> 16;
        u[i * 8 + 6] = v.w & 0xFFFFu; u[i * 8 + 7] = v.w >> 16;
    }

    // diagonal: column grow lives at lane (grow>>3)&63, slot ((grow>>9)<<3)|(grow&7)
    const int dl = (grow >> 3) & 63;
    const int dk = ((grow >> 9) << 3) | (grow & 7);
    unsigned dv = 0;
#pragma unroll
    for (int k = 0; k < 64; ++k)
        if (k == dk) dv = u[k];
    const unsigned dku = (unsigned)__shfl((int)dv, dl, 64);

    // ====== 20th smallest: largest T with cnt(<T) < K ======
    unsigned lo = 0, hi = 65536;
    int clo = 0;
    while (hi - lo > 1u) {
        const unsigned mid = (lo + hi) >> 1;
        int c = 0;
#pragma unroll
        for (int k = 0; k < 64; ++k)
            c += (int)__popcll(__ballot(u[k] < mid));
        c -= (dku < mid) ? 1 : 0;
        if (c < KSEL) { lo = mid; clo = c; } else hi = mid;
    }
    const unsigned Tmin = lo;
    int s = 0;
#pragma unroll
    for (int k = 0; k < 64; ++k)
        if (u[k] < Tmin) s += (int)u[k];
#pragma unroll
    for (int off = 32; off; off >>= 1) s += __shfl_xor(s, off, 64);
    const int sum_min_i = s - ((dku < Tmin) ? (int)dku : 0) + (KSEL - clo) * (int)Tmin;

    // ====== 20th largest: smallest T with cnt(>T) < K ======
    int lo2 = -1, hi2 = 65535;
    int chi = 0;
    while (hi2 - lo2 > 1) {
        const int mid = (lo2 + hi2) >> 1;
        int c = 0;
#pragma unroll
        for (int k = 0; k < 64; ++k)
            c += (int)__popcll(__ballot((int)u[k] > mid));
        c -= ((int)dku > mid) ? 1 : 0;
        if (c < KSEL) { hi2 = mid; chi = c; } else lo2 = mid;
    }
    const int Tmax = hi2;
    s = 0;
#pragma unroll
    for (int k = 0; k < 64; ++k)
        if ((int)u[k] > Tmax) s += (int)u[k];
#pragma unroll
    for (int off = 32; off; off >>= 1) s += __shfl_xor(s, off, 64);
    const int sum_max_i = s - (((int)dku > Tmax) ? (int)dku : 0) + (KSEL - chi) * Tmax;

    if (lane == 0) {
        const float inv = 1.0f / 65535.0f;
        const float total = (float)(sum_min_i + sum_max_i) * inv;
        const float dap = (float)dku * inv;
        const float neg = -0.0125f * total;  // -((1-prior)/(2K)) * sum
        const float pos = 0.5f * dap;        // prior * dist_ap
        loss[grow] = (neg < 0.f) ? -neg : (pos + neg);
    }
}

// ---------------------------------------------------------------------------
// Kernel 4: deterministic mean of loss[0..N-1] -> out[0]
// ---------------------------------------------------------------------------
__global__ __launch_bounds__(256) void finalize_kernel(const float* __restrict__ loss,
                                                       float* __restrict__ out) {
    const int tid = threadIdx.x;
    float s = 0.f;
    for (int k = tid; k < NROW; k += 256) s += loss[k];
#pragma unroll
    for (int off = 32; off; off >>= 1) s += __shfl_xor(s, off, 64);
    __shared__ float p[4];
    if ((tid & 63) == 0) p[tid >> 6] = s;
    __syncthreads();
    if (tid == 0) out[0] = (p[0] + p[1] + p[2] + p[3]) * (1.0f / (float)NROW);
}

// ---------------------------------------------------------------------------
extern "C" void kernel_launch(void* const* d_in, const int* in_sizes, int n_in,
                              void* d_out, int out_size, void* d_ws, size_t ws_size,
                              hipStream_t stream) {
    const float* A = (const float*)d_in[0];  // input  [N,C] f32
    const float* B = (const float*)d_in[1];  // target [N,C] f32

    char* ws = (char*)d_ws;
    const size_t norm_bytes = (size_t)NROW * CDIM * 2;        // 2 MB each
    ushort* An    = (ushort*)ws;
    ushort* Bn    = (ushort*)(ws + norm_bytes);
    float*  lossv = (float*)(ws + 2 * norm_bytes);            // 16 KB
    ushort* dist16 = (ushort*)(ws + 2 * norm_bytes + NROW * 4);
    const size_t fixed = 2 * norm_bytes + (size_t)NROW * 4;

    // band rows sized to fit ws (8 KB per row); floor at 128 (GEMM tile height)
    int band = NROW;
    while (band > 128 && fixed + (size_t)band * NROW * 2 > ws_size) band >>= 1;

    prep_kernel<<<2 * NROW, 256, 0, stream>>>(A, B, An, Bn);
    for (int r0 = 0; r0 < NROW; r0 += band) {
        gemm16_kernel<<<dim3(NROW / 128, band / 128), 256, 0, stream>>>(An, Bn, dist16, r0);
        select_kernel<<<band / 4, 256, 0, stream>>>(dist16, lossv, r0);
    }
    finalize_kernel<<<1, 256, 0, stream>>>(lossv, (float*)d_out);
}

// Round 4
// 77.037 us; speedup vs baseline: 10.3586x; 1.2741x over previous
//
#include <hip/hip_runtime.h>
#include <hip/hip_bf16.h>
#include <math.h>

#define NROW 4096
#define CDIM 256
#define KSEL 20

typedef __attribute__((ext_vector_type(8))) short short8_t;  // 8 bf16 (4 VGPRs)
typedef __attribute__((ext_vector_type(4))) float f32x4;
typedef const __attribute__((address_space(1))) unsigned g_u32;
typedef __attribute__((address_space(3))) unsigned l_u32;

// ---------------------------------------------------------------------------
// Kernel 1: normalize rows of A and B, store as bf16.
// ---------------------------------------------------------------------------
__global__ __launch_bounds__(256) void prep_kernel(const float* __restrict__ A,
                                                   const float* __restrict__ B,
                                                   ushort* __restrict__ An,
                                                   ushort* __restrict__ Bn) {
    const int bid = blockIdx.x;
    const int row = bid & (NROW - 1);
    const float* __restrict__ X = (bid < NROW) ? A : B;
    ushort* __restrict__ Y = (bid < NROW) ? An : Bn;
    const int tid = threadIdx.x;
    float v = X[(size_t)row * CDIM + tid];
    float s = v * v;
#pragma unroll
    for (int off = 32; off; off >>= 1) s += __shfl_xor(s, off, 64);
    __shared__ float p[4];
    __shared__ float rsh;
    if ((tid & 63) == 0) p[tid >> 6] = s;
    __syncthreads();
    if (tid == 0) rsh = 1.0f / fmaxf(sqrtf(p[0] + p[1] + p[2] + p[3]), 1e-12f);
    __syncthreads();
    __hip_bfloat16 h = __float2bfloat16(v * rsh);
    Y[(size_t)row * CDIM + tid] = *(ushort*)&h;
}

// ---------------------------------------------------------------------------
// Kernel 2: bf16 MFMA GEMM (m97 structure: 128x128 tile, BK=64, LDS staged
// via global_load_lds width-16, single-buffered, 2 barriers per K-step).
// dist quantized to u16: key = round(clamp((1-dot)*0.5,0,1)*65535).
// Fragment mapping identical to the round-3-verified kernel.
// ---------------------------------------------------------------------------
__global__ __launch_bounds__(256) void gemm16_kernel(const ushort* __restrict__ An,
                                                     const ushort* __restrict__ Bn,
                                                     ushort* __restrict__ dist16,
                                                     int r0) {
    const int tid  = threadIdx.x;
    const int lane = tid & 63;
    const int wid  = tid >> 6;
    const int wm = wid >> 1, wn = wid & 1;
    const int ib = blockIdx.y * 128;            // band-local row base of tile
    const int i0 = r0 + ib;                     // global row base of tile
    const int j0 = blockIdx.x * 128;
    const int lr  = lane & 15;
    const int lk8 = (lane >> 4) * 8;

    __shared__ ushort As[128 * 64];   // 16 KB, rows x BK, linear
    __shared__ ushort Bs[128 * 64];   // 16 KB

    // staging geometry: thread t covers LDS bytes [t*16, t*16+16) per round r
    // -> bf16 row (t>>3) + r*32, col (t&7)*8 of the 128x64 tile.
    const int srow = tid >> 3;        // 0..31
    const int scol = (tid & 7) * 8;   // 0..56
    const unsigned wbase = (unsigned)(wid * 1024);  // wave-uniform LDS byte base

    f32x4 acc[4][4];
#pragma unroll
    for (int m = 0; m < 4; ++m)
#pragma unroll
        for (int n = 0; n < 4; ++n) acc[m][n] = (f32x4){0.f, 0.f, 0.f, 0.f};

#pragma unroll
    for (int ks = 0; ks < CDIM / 64; ++ks) {
        const int k0 = ks * 64;
        // ---- stage A,B tiles (4 rounds x 2 tiles of global_load_lds x16B) ----
#pragma unroll
        for (int r = 0; r < 4; ++r) {
            const ushort* ga = An + (size_t)(i0 + r * 32 + srow) * CDIM + k0 + scol;
            __builtin_amdgcn_global_load_lds((g_u32*)ga,
                (l_u32*)((char*)As + r * 4096 + wbase), 16, 0, 0);
        }
#pragma unroll
        for (int r = 0; r < 4; ++r) {
            const ushort* gb = Bn + (size_t)(j0 + r * 32 + srow) * CDIM + k0 + scol;
            __builtin_amdgcn_global_load_lds((g_u32*)gb,
                (l_u32*)((char*)Bs + r * 4096 + wbase), 16, 0, 0);
        }
        __syncthreads();   // drains vmcnt before reads

        // ---- compute: 2 sub-steps of K=32, 8 ds_read_b128 + 16 MFMA each ----
#pragma unroll
        for (int kk = 0; kk < 2; ++kk) {
            const int coff = kk * 32 + lk8;
            short8_t a[4], b[4];
#pragma unroll
            for (int m = 0; m < 4; ++m)
                a[m] = *(const short8_t*)&As[(wm * 64 + m * 16 + lr) * 64 + coff];
#pragma unroll
            for (int n = 0; n < 4; ++n)
                b[n] = *(const short8_t*)&Bs[(wn * 64 + n * 16 + lr) * 64 + coff];
#pragma unroll
            for (int m = 0; m < 4; ++m)
#pragma unroll
                for (int n = 0; n < 4; ++n)
                    acc[m][n] = __builtin_amdgcn_mfma_f32_16x16x32_bf16(a[m], b[n], acc[m][n], 0, 0, 0);
        }
        __syncthreads();   // before next stage overwrites
    }

    // ---- epilogue: quantize + store (C/D layout: row=(lane>>4)*4+q, col=lane&15) ----
    const int orow = (lane >> 4) * 4;
    const int ocol = lane & 15;
#pragma unroll
    for (int m = 0; m < 4; ++m) {
#pragma unroll
        for (int q = 0; q < 4; ++q) {
            const int irow = ib + wm * 64 + m * 16 + orow + q;  // band-local row
#pragma unroll
            for (int n = 0; n < 4; ++n) {
                float d = (1.0f - acc[m][n][q]) * 0.5f;
                d = fminf(fmaxf(d, 0.0f), 1.0f);
                unsigned key = __float2uint_rn(d * 65535.0f);
                dist16[(size_t)irow * NROW + (j0 + wn * 64 + n * 16 + ocol)] = (ushort)key;
            }
        }
    }
}

// ---------------------------------------------------------------------------
// Kernel 3: per-row top-K selection on u16 keys. One wave per row.
// Dual (min & max) binary search interleaved, per-lane VALU counting
// (no ballot/popc -> no shared-SALU bottleneck), one packed reduce per iter.
// ---------------------------------------------------------------------------
__global__ __launch_bounds__(256) void select_kernel(const ushort* __restrict__ dist16,
                                                     float* __restrict__ loss, int r0) {
    const int tid  = threadIdx.x;
    const int lane = tid & 63;
    const int wid  = tid >> 6;
    const int rb   = blockIdx.x * 4 + wid;  // band-local row
    const int grow = r0 + rb;               // global row

    const uint4* __restrict__ P = (const uint4*)(dist16 + (size_t)rb * NROW);
    unsigned u[64];
#pragma unroll
    for (int i = 0; i < 8; ++i) {
        uint4 v = P[i * 64 + lane];
        u[i * 8 + 0] = v.x & 0xFFFFu; u[i * 8 + 1] = v.x >> 16;
        u[i * 8 + 2] = v.y & 0xFFFFu; u[i * 8 + 3] = v.y >> 16;
        u[i * 8 + 4] = v.z & 0xFFFFu; u[i * 8 + 5] = v.z >> 16;
        u[i * 8 + 6] = v.w & 0xFFFFu; u[i * 8 + 7] = v.w >> 16;
    }

    // diagonal: column grow lives at lane (grow>>3)&63, slot ((grow>>9)<<3)|(grow&7)
    const int dl = (grow >> 3) & 63;
    const int dk = ((grow >> 9) << 3) | (grow & 7);
    unsigned dv = 0;
#pragma unroll
    for (int k = 0; k < 64; ++k)
        if (k == dk) dv = u[k];
    const unsigned dku = (unsigned)__shfl((int)dv, dl, 64);

    // ---- dual binary search, exactly 16 iterations (range = 2^16) ----
    unsigned lo1 = 0, hi1 = 65536; int clo = 0;   // min side: largest T, cnt(<T) < K
    int lo2 = -1, hi2 = 65535; int chi = 0;       // max side: smallest T, cnt(>T) < K
#pragma unroll 1
    for (int it = 0; it < 16; ++it) {
        const unsigned mid1 = (lo1 + hi1) >> 1;
        const int      mid2 = (lo2 + hi2) >> 1;
        int c1 = 0, c2 = 0;
#pragma unroll
        for (int k = 0; k < 64; ++k) {
            c1 += (u[k] < mid1) ? 1 : 0;
            c2 += ((int)u[k] > mid2) ? 1 : 0;
        }
        int cc = c1 | (c2 << 16);
#pragma unroll
        for (int off = 32; off; off >>= 1) cc += __shfl_xor(cc, off, 64);
        c1 = (cc & 0xFFFF) - ((dku < mid1) ? 1 : 0);
        c2 = (cc >> 16) - (((int)dku > mid2) ? 1 : 0);
        if (c1 < KSEL) { lo1 = mid1; clo = c1; } else hi1 = mid1;
        if (c2 < KSEL) { hi2 = mid2; chi = c2; } else lo2 = mid2;
    }
    const unsigned Tmin = lo1;
    const int      Tmax = hi2;

    // ---- fused strict-side sums ----
    int s1 = 0, s2 = 0;
#pragma unroll
    for (int k = 0; k < 64; ++k) {
        s1 += (u[k] < Tmin) ? (int)u[k] : 0;
        s2 += ((int)u[k] > Tmax) ? (int)u[k] : 0;
    }
#pragma unroll
    for (int off = 32; off; off >>= 1) {
        s1 += __shfl_xor(s1, off, 64);
        s2 += __shfl_xor(s2, off, 64);
    }
    const int sum_min_i = s1 - ((dku < Tmin) ? (int)dku : 0) + (KSEL - clo) * (int)Tmin;
    const int sum_max_i = s2 - (((int)dku > Tmax) ? (int)dku : 0) + (KSEL - chi) * Tmax;

    if (lane == 0) {
        const float inv = 1.0f / 65535.0f;
        const float total = (float)(sum_min_i + sum_max_i) * inv;
        const float dap = (float)dku * inv;
        const float neg = -0.0125f * total;  // -((1-prior)/(2K)) * sum
        const float pos = 0.5f * dap;        // prior * dist_ap
        loss[grow] = (neg < 0.f) ? -neg : (pos + neg);
    }
}

// ---------------------------------------------------------------------------
// Kernel 4: deterministic mean of loss[0..N-1] -> out[0]
// ---------------------------------------------------------------------------
__global__ __launch_bounds__(256) void finalize_kernel(const float* __restrict__ loss,
                                                       float* __restrict__ out) {
    const int tid = threadIdx.x;
    float s = 0.f;
    for (int k = tid; k < NROW; k += 256) s += loss[k];
#pragma unroll
    for (int off = 32; off; off >>= 1) s += __shfl_xor(s, off, 64);
    __shared__ float p[4];
    if ((tid & 63) == 0) p[tid >> 6] = s;
    __syncthreads();
    if (tid == 0) out[0] = (p[0] + p[1] + p[2] + p[3]) * (1.0f / (float)NROW);
}

// ---------------------------------------------------------------------------
extern "C" void kernel_launch(void* const* d_in, const int* in_sizes, int n_in,
                              void* d_out, int out_size, void* d_ws, size_t ws_size,
                              hipStream_t stream) {
    const float* A = (const float*)d_in[0];  // input  [N,C] f32
    const float* B = (const float*)d_in[1];  // target [N,C] f32

    char* ws = (char*)d_ws;
    const size_t norm_bytes = (size_t)NROW * CDIM * 2;        // 2 MB each
    ushort* An    = (ushort*)ws;
    ushort* Bn    = (ushort*)(ws + norm_bytes);
    float*  lossv = (float*)(ws + 2 * norm_bytes);            // 16 KB
    ushort* dist16 = (ushort*)(ws + 2 * norm_bytes + NROW * 4);
    const size_t fixed = 2 * norm_bytes + (size_t)NROW * 4;

    // band rows sized to fit ws (8 KB per row); floor at 128 (GEMM tile height)
    int band = NROW;
    while (band > 128 && fixed + (size_t)band * NROW * 2 > ws_size) band >>= 1;

    prep_kernel<<<2 * NROW, 256, 0, stream>>>(A, B, An, Bn);
    for (int r0 = 0; r0 < NROW; r0 += band) {
        gemm16_kernel<<<dim3(NROW / 128, band / 128), 256, 0, stream>>>(An, Bn, dist16, r0);
        select_kernel<<<band / 4, 256, 0, stream>>>(dist16, lossv, r0);
    }
    finalize_kernel<<<1, 256, 0, stream>>>(lossv, (float*)d_out);
}

// Round 5
// 48.744 us; speedup vs baseline: 16.3712x; 1.5804x over previous
//
#include <hip/hip_runtime.h>
#include <hip/hip_bf16.h>
#include <math.h>

#define NROW 4096
#define CDIM 256
#define KSEL 20

typedef __attribute__((ext_vector_type(8))) short short8_t;  // 8 bf16 (4 VGPRs)
typedef __attribute__((ext_vector_type(4))) float f32x4;
typedef const __attribute__((address_space(1))) unsigned g_u32;
typedef __attribute__((address_space(3))) unsigned l_u32;

__device__ __forceinline__ unsigned sad_u8(unsigned a, unsigned b, unsigned c) {
    unsigned d;
    asm("v_sad_u8 %0, %1, %2, %3" : "=v"(d) : "v"(a), "v"(b), "v"(c));
    return d;
}

// ---------------------------------------------------------------------------
// Kernel 1: normalize rows of A and B, store as bf16.
// ---------------------------------------------------------------------------
__global__ __launch_bounds__(256) void prep_kernel(const float* __restrict__ A,
                                                   const float* __restrict__ B,
                                                   ushort* __restrict__ An,
                                                   ushort* __restrict__ Bn) {
    const int bid = blockIdx.x;
    const int row = bid & (NROW - 1);
    const float* __restrict__ X = (bid < NROW) ? A : B;
    ushort* __restrict__ Y = (bid < NROW) ? An : Bn;
    const int tid = threadIdx.x;
    float v = X[(size_t)row * CDIM + tid];
    float s = v * v;
#pragma unroll
    for (int off = 32; off; off >>= 1) s += __shfl_xor(s, off, 64);
    __shared__ float p[4];
    __shared__ float rsh;
    if ((tid & 63) == 0) p[tid >> 6] = s;
    __syncthreads();
    if (tid == 0) rsh = 1.0f / fmaxf(sqrtf(p[0] + p[1] + p[2] + p[3]), 1e-12f);
    __syncthreads();
    __hip_bfloat16 h = __float2bfloat16(v * rsh);
    Y[(size_t)row * CDIM + tid] = *(ushort*)&h;
}

// ---------------------------------------------------------------------------
// Kernel 2: bf16 MFMA GEMM (m97 structure: 128x128 tile, BK=64, LDS staged
// via global_load_lds width-16, single-buffered, 2 barriers per K-step).
// dist quantized to 7-bit: key = round(clamp((1-dot)*0.5,0,1)*127), u8 store.
// ---------------------------------------------------------------------------
__global__ __launch_bounds__(256) void gemm16_kernel(const ushort* __restrict__ An,
                                                     const ushort* __restrict__ Bn,
                                                     unsigned char* __restrict__ dist8,
                                                     int r0) {
    const int tid  = threadIdx.x;
    const int lane = tid & 63;
    const int wid  = tid >> 6;
    const int wm = wid >> 1, wn = wid & 1;
    const int ib = blockIdx.y * 128;            // band-local row base of tile
    const int i0 = r0 + ib;                     // global row base of tile
    const int j0 = blockIdx.x * 128;
    const int lr  = lane & 15;
    const int lk8 = (lane >> 4) * 8;

    __shared__ ushort As[128 * 64];   // 16 KB, rows x BK, linear
    __shared__ ushort Bs[128 * 64];   // 16 KB

    const int srow = tid >> 3;        // 0..31
    const int scol = (tid & 7) * 8;   // 0..56
    const unsigned wbase = (unsigned)(wid * 1024);  // wave-uniform LDS byte base

    f32x4 acc[4][4];
#pragma unroll
    for (int m = 0; m < 4; ++m)
#pragma unroll
        for (int n = 0; n < 4; ++n) acc[m][n] = (f32x4){0.f, 0.f, 0.f, 0.f};

#pragma unroll
    for (int ks = 0; ks < CDIM / 64; ++ks) {
        const int k0 = ks * 64;
#pragma unroll
        for (int r = 0; r < 4; ++r) {
            const ushort* ga = An + (size_t)(i0 + r * 32 + srow) * CDIM + k0 + scol;
            __builtin_amdgcn_global_load_lds((g_u32*)ga,
                (l_u32*)((char*)As + r * 4096 + wbase), 16, 0, 0);
        }
#pragma unroll
        for (int r = 0; r < 4; ++r) {
            const ushort* gb = Bn + (size_t)(j0 + r * 32 + srow) * CDIM + k0 + scol;
            __builtin_amdgcn_global_load_lds((g_u32*)gb,
                (l_u32*)((char*)Bs + r * 4096 + wbase), 16, 0, 0);
        }
        __syncthreads();   // drains vmcnt before reads

#pragma unroll
        for (int kk = 0; kk < 2; ++kk) {
            const int coff = kk * 32 + lk8;
            short8_t a[4], b[4];
#pragma unroll
            for (int m = 0; m < 4; ++m)
                a[m] = *(const short8_t*)&As[(wm * 64 + m * 16 + lr) * 64 + coff];
#pragma unroll
            for (int n = 0; n < 4; ++n)
                b[n] = *(const short8_t*)&Bs[(wn * 64 + n * 16 + lr) * 64 + coff];
#pragma unroll
            for (int m = 0; m < 4; ++m)
#pragma unroll
                for (int n = 0; n < 4; ++n)
                    acc[m][n] = __builtin_amdgcn_mfma_f32_16x16x32_bf16(a[m], b[n], acc[m][n], 0, 0, 0);
        }
        __syncthreads();   // before next stage overwrites
    }

    // ---- epilogue: 7-bit quantize + byte store (row=(lane>>4)*4+q, col=lane&15) ----
    const int orow = (lane >> 4) * 4;
    const int ocol = lane & 15;
#pragma unroll
    for (int m = 0; m < 4; ++m) {
#pragma unroll
        for (int q = 0; q < 4; ++q) {
            const int irow = ib + wm * 64 + m * 16 + orow + q;  // band-local row
#pragma unroll
            for (int n = 0; n < 4; ++n) {
                float d = (1.0f - acc[m][n][q]) * 0.5f;
                d = fminf(fmaxf(d, 0.0f), 1.0f);
                unsigned key = __float2uint_rn(d * 127.0f);
                dist8[(size_t)irow * NROW + (j0 + wn * 64 + n * 16 + ocol)] = (unsigned char)key;
            }
        }
    }
}

// ---------------------------------------------------------------------------
// Kernel 3: per-row top-K on 7-bit keys, one wave per row.
// SWAR byte counting: z = ((127+T)*0x01010101 - x) & 0x80808080 marks bytes
// x < T (borrow-free since bytes<=127); v_sad_u8 accumulates 128*count.
// Dual search in 7 iterations; max side via complement counts/sums.
// ---------------------------------------------------------------------------
__global__ __launch_bounds__(256) void select_kernel(const unsigned char* __restrict__ dist8,
                                                     float* __restrict__ loss, int r0) {
    const int tid  = threadIdx.x;
    const int lane = tid & 63;
    const int wid  = tid >> 6;
    const int rb   = blockIdx.x * 4 + wid;  // band-local row
    const int grow = r0 + rb;               // global row

    const uint4* __restrict__ P = (const uint4*)(dist8 + (size_t)rb * NROW);
    unsigned w[16];
#pragma unroll
    for (int i = 0; i < 4; ++i) {
        uint4 v = P[i * 64 + lane];
        w[4 * i + 0] = v.x; w[4 * i + 1] = v.y;
        w[4 * i + 2] = v.z; w[4 * i + 3] = v.w;
    }
    const unsigned dku = (unsigned)dist8[(size_t)rb * NROW + grow];  // diagonal key
    const unsigned M = 0x80808080u;
    const unsigned zero = 0u;

    // total row byte-sum (per lane), reduced later
    unsigned rs = 0;
#pragma unroll
    for (int i = 0; i < 16; ++i) rs = sad_u8(w[i], zero, rs);

    // ---- dual binary search over T in [0,128], 7 iterations ----
    int lo1 = 0, hi1 = 128, clo = 0;   // min side: largest T with cnt(<T) < K
    int lo2 = -1, hi2 = 127, chi = 0;  // max side: smallest T with cnt(>T) < K
#pragma unroll 1
    for (int it = 0; it < 7; ++it) {
        const int mid1 = (lo1 + hi1) >> 1;
        const int mid2 = (lo2 + hi2) >> 1;
        const unsigned C1 = (unsigned)(127 + mid1) * 0x01010101u;
        const unsigned C2 = (unsigned)(128 + mid2) * 0x01010101u;  // cntlt(mid2+1)
        unsigned a1 = 0, a2 = 0;
#pragma unroll
        for (int i = 0; i < 16; ++i) {
            a1 = sad_u8((C1 - w[i]) & M, zero, a1);
            a2 = sad_u8((C2 - w[i]) & M, zero, a2);
        }
        int cc = (int)((a1 >> 7) | ((a2 >> 7) << 16));
#pragma unroll
        for (int off = 32; off; off >>= 1) cc += __shfl_xor(cc, off, 64);
        cc = __builtin_amdgcn_readfirstlane(cc);
        const int c1 = (cc & 0xFFFF) - ((dku < (unsigned)mid1) ? 1 : 0);
        const int c2 = (4096 - (cc >> 16)) - (((int)dku > mid2) ? 1 : 0);
        if (c1 < KSEL) { lo1 = mid1; clo = c1; } else hi1 = mid1;
        if (c2 < KSEL) { hi2 = mid2; chi = c2; } else lo2 = mid2;
    }
    const int Tmin = lo1, Tmax = hi2;

    // ---- masked sums: sumlt(Tmin), sumlt(Tmax+1) ----
    const unsigned CA = (unsigned)(127 + Tmin) * 0x01010101u;
    const unsigned CB = (unsigned)(128 + Tmax) * 0x01010101u;
    unsigned sA = 0, sB = 0;
#pragma unroll
    for (int i = 0; i < 16; ++i) {
        const unsigned mA = ((CA - w[i]) & M) >> 7;
        sA = sad_u8(w[i] & ((mA << 8) - mA), zero, sA);
        const unsigned mB = ((CB - w[i]) & M) >> 7;
        sB = sad_u8(w[i] & ((mB << 8) - mB), zero, sB);
    }
#pragma unroll
    for (int off = 32; off; off >>= 1) {
        rs += __shfl_xor(rs, off, 64);
        sA += __shfl_xor(sA, off, 64);
        sB += __shfl_xor(sB, off, 64);
    }

    const int sum_min_i = (int)sA - ((dku < (unsigned)Tmin) ? (int)dku : 0)
                        + (KSEL - clo) * Tmin;
    const int sum_gt    = (int)(rs - sB);  // sum of keys > Tmax (incl diag)
    const int sum_max_i = sum_gt - (((int)dku > Tmax) ? (int)dku : 0)
                        + (KSEL - chi) * Tmax;

    if (lane == 0) {
        const float inv = 1.0f / 127.0f;
        const float total = (float)(sum_min_i + sum_max_i) * inv;
        const float dap = (float)dku * inv;
        const float neg = -0.0125f * total;  // -((1-prior)/(2K)) * sum
        const float pos = 0.5f * dap;        // prior * dist_ap
        loss[grow] = (neg < 0.f) ? -neg : (pos + neg);
    }
}

// ---------------------------------------------------------------------------
// Kernel 4: deterministic mean of loss[0..N-1] -> out[0]
// ---------------------------------------------------------------------------
__global__ __launch_bounds__(256) void finalize_kernel(const float* __restrict__ loss,
                                                       float* __restrict__ out) {
    const int tid = threadIdx.x;
    float s = 0.f;
    for (int k = tid; k < NROW; k += 256) s += loss[k];
#pragma unroll
    for (int off = 32; off; off >>= 1) s += __shfl_xor(s, off, 64);
    __shared__ float p[4];
    if ((tid & 63) == 0) p[tid >> 6] = s;
    __syncthreads();
    if (tid == 0) out[0] = (p[0] + p[1] + p[2] + p[3]) * (1.0f / (float)NROW);
}

// ---------------------------------------------------------------------------
extern "C" void kernel_launch(void* const* d_in, const int* in_sizes, int n_in,
                              void* d_out, int out_size, void* d_ws, size_t ws_size,
                              hipStream_t stream) {
    const float* A = (const float*)d_in[0];  // input  [N,C] f32
    const float* B = (const float*)d_in[1];  // target [N,C] f32

    char* ws = (char*)d_ws;
    const size_t norm_bytes = (size_t)NROW * CDIM * 2;        // 2 MB each
    ushort* An    = (ushort*)ws;
    ushort* Bn    = (ushort*)(ws + norm_bytes);
    float*  lossv = (float*)(ws + 2 * norm_bytes);            // 16 KB
    unsigned char* dist8 = (unsigned char*)(ws + 2 * norm_bytes + NROW * 4);
    const size_t fixed = 2 * norm_bytes + (size_t)NROW * 4;

    // band rows sized to fit ws (4 KB per row); floor at 128 (GEMM tile height)
    int band = NROW;
    while (band > 128 && fixed + (size_t)band * NROW > ws_size) band >>= 1;

    prep_kernel<<<2 * NROW, 256, 0, stream>>>(A, B, An, Bn);
    for (int r0 = 0; r0 < NROW; r0 += band) {
        gemm16_kernel<<<dim3(NROW / 128, band / 128), 256, 0, stream>>>(An, Bn, dist8, r0);
        select_kernel<<<band / 4, 256, 0, stream>>>(dist8, lossv, r0);
    }
    finalize_kernel<<<1, 256, 0, stream>>>(lossv, (float*)d_out);
}

// Round 6
// 46.261 us; speedup vs baseline: 17.2499x; 1.0537x over previous
//
#include <hip/hip_runtime.h>
#include <hip/hip_bf16.h>
#include <math.h>

#define NROW 4096
#define CDIM 256
#define KSEL 20

typedef __attribute__((ext_vector_type(8))) short short8_t;  // 8 bf16 (4 VGPRs)
typedef __attribute__((ext_vector_type(4))) float f32x4;
typedef const __attribute__((address_space(1))) unsigned g_u32;
typedef __attribute__((address_space(3))) unsigned l_u32;

__device__ __forceinline__ unsigned sad_u8(unsigned a, unsigned b, unsigned c) {
    unsigned d;
    asm("v_sad_u8 %0, %1, %2, %3" : "=v"(d) : "v"(a), "v"(b), "v"(c));
    return d;
}

// ---------------------------------------------------------------------------
// Kernel 1: normalize rows of A and B, store as bf16. Wave-per-row,
// barrier-free: lane holds 4 elems (float4), butterfly reduce, ushort4 store.
// grid = 2*NROW/4 blocks x 256 threads.
// ---------------------------------------------------------------------------
__global__ __launch_bounds__(256) void prep_kernel(const float* __restrict__ A,
                                                   const float* __restrict__ B,
                                                   ushort* __restrict__ An,
                                                   ushort* __restrict__ Bn) {
    const int tid  = threadIdx.x;
    const int lane = tid & 63;
    const int wid  = tid >> 6;
    const int r    = blockIdx.x * 4 + wid;   // 0..8191
    const int row  = r & (NROW - 1);
    const float* __restrict__ X = (r < NROW) ? A : B;
    ushort* __restrict__ Y = (r < NROW) ? An : Bn;

    const float4 v = ((const float4*)(X + (size_t)row * CDIM))[lane];
    float s = v.x * v.x + v.y * v.y + v.z * v.z + v.w * v.w;
#pragma unroll
    for (int off = 32; off; off >>= 1) s += __shfl_xor(s, off, 64);
    const float rinv = 1.0f / fmaxf(sqrtf(s), 1e-12f);

    ushort4 o;
    __hip_bfloat16 h0 = __float2bfloat16(v.x * rinv); o.x = *(ushort*)&h0;
    __hip_bfloat16 h1 = __float2bfloat16(v.y * rinv); o.y = *(ushort*)&h1;
    __hip_bfloat16 h2 = __float2bfloat16(v.z * rinv); o.z = *(ushort*)&h2;
    __hip_bfloat16 h3 = __float2bfloat16(v.w * rinv); o.w = *(ushort*)&h3;
    ((ushort4*)(Y + (size_t)row * CDIM))[lane] = o;
}

// ---------------------------------------------------------------------------
// Kernel 2: bf16 MFMA GEMM, 128x128 tile, BK=64, DOUBLE-buffered LDS
// (T3 minimum 2-phase: stage(next) -> compute(cur) -> syncthreads; the
// barrier's implicit vmcnt(0) lands after the MFMA cluster, hiding the
// next tile's load latency under compute). XCD-aware bijective swizzle.
// dist quantized to 7-bit: key = round(clamp((1-dot)*0.5,0,1)*127), u8 store.
// ---------------------------------------------------------------------------
__global__ __launch_bounds__(256) void gemm16_kernel(const ushort* __restrict__ An,
                                                     const ushort* __restrict__ Bn,
                                                     unsigned char* __restrict__ dist8,
                                                     int r0) {
    const int tid  = threadIdx.x;
    const int lane = tid & 63;
    const int wid  = tid >> 6;
    const int wm = wid >> 1, wn = wid & 1;

    // bijective XCD swizzle: consecutive wg on one XCD share A-panels
    const int nwg  = gridDim.x * gridDim.y;
    const int flat = blockIdx.y * gridDim.x + blockIdx.x;
    const int wg   = (flat & 7) * (nwg >> 3) + (flat >> 3);
    const int bx   = wg & 31;          // j tile (gridDim.x == 32)
    const int byt  = wg >> 5;          // band-local i tile

    const int ib = byt * 128;                   // band-local row base of tile
    const int i0 = r0 + ib;                     // global row base of tile
    const int j0 = bx * 128;
    const int lr  = lane & 15;
    const int lk8 = (lane >> 4) * 8;

    __shared__ ushort As[2][128 * 64];   // 2 x 16 KB
    __shared__ ushort Bs[2][128 * 64];   // 2 x 16 KB

    const int srow = tid >> 3;        // 0..31
    const int scol = (tid & 7) * 8;   // 0..56
    const unsigned wbase = (unsigned)(wid * 1024);  // wave-uniform LDS byte base

    f32x4 acc[4][4];
#pragma unroll
    for (int m = 0; m < 4; ++m)
#pragma unroll
        for (int n = 0; n < 4; ++n) acc[m][n] = (f32x4){0.f, 0.f, 0.f, 0.f};

    // ---- prologue: stage tile 0 into buffer 0 ----
#pragma unroll
    for (int r = 0; r < 4; ++r) {
        const ushort* ga = An + (size_t)(i0 + r * 32 + srow) * CDIM + scol;
        __builtin_amdgcn_global_load_lds((g_u32*)ga,
            (l_u32*)((char*)As[0] + r * 4096 + wbase), 16, 0, 0);
        const ushort* gb = Bn + (size_t)(j0 + r * 32 + srow) * CDIM + scol;
        __builtin_amdgcn_global_load_lds((g_u32*)gb,
            (l_u32*)((char*)Bs[0] + r * 4096 + wbase), 16, 0, 0);
    }
    __syncthreads();

#pragma unroll
    for (int ks = 0; ks < 4; ++ks) {
        const int cur = ks & 1;
        // ---- stage next tile into the other buffer (overlaps with MFMA) ----
        if (ks < 3) {
            const int k0 = (ks + 1) * 64;
#pragma unroll
            for (int r = 0; r < 4; ++r) {
                const ushort* ga = An + (size_t)(i0 + r * 32 + srow) * CDIM + k0 + scol;
                __builtin_amdgcn_global_load_lds((g_u32*)ga,
                    (l_u32*)((char*)As[cur ^ 1] + r * 4096 + wbase), 16, 0, 0);
                const ushort* gb = Bn + (size_t)(j0 + r * 32 + srow) * CDIM + k0 + scol;
                __builtin_amdgcn_global_load_lds((g_u32*)gb,
                    (l_u32*)((char*)Bs[cur ^ 1] + r * 4096 + wbase), 16, 0, 0);
            }
        }
        // ---- compute current buffer: 2 sub-steps of K=32 ----
#pragma unroll
        for (int kk = 0; kk < 2; ++kk) {
            const int coff = kk * 32 + lk8;
            short8_t a[4], b[4];
#pragma unroll
            for (int m = 0; m < 4; ++m)
                a[m] = *(const short8_t*)&As[cur][(wm * 64 + m * 16 + lr) * 64 + coff];
#pragma unroll
            for (int n = 0; n < 4; ++n)
                b[n] = *(const short8_t*)&Bs[cur][(wn * 64 + n * 16 + lr) * 64 + coff];
#pragma unroll
            for (int m = 0; m < 4; ++m)
#pragma unroll
                for (int n = 0; n < 4; ++n)
                    acc[m][n] = __builtin_amdgcn_mfma_f32_16x16x32_bf16(a[m], b[n], acc[m][n], 0, 0, 0);
        }
        // barrier: implicit vmcnt(0) waits the next tile's loads AFTER compute,
        // and protects buf[cur] from being restaged next iteration.
        __syncthreads();
    }

    // ---- epilogue: 7-bit quantize + byte store (row=(lane>>4)*4+q, col=lane&15) ----
    const int orow = (lane >> 4) * 4;
    const int ocol = lane & 15;
#pragma unroll
    for (int m = 0; m < 4; ++m) {
#pragma unroll
        for (int q = 0; q < 4; ++q) {
            const int irow = ib + wm * 64 + m * 16 + orow + q;  // band-local row
#pragma unroll
            for (int n = 0; n < 4; ++n) {
                float d = (1.0f - acc[m][n][q]) * 0.5f;
                d = fminf(fmaxf(d, 0.0f), 1.0f);
                unsigned key = __float2uint_rn(d * 127.0f);
                dist8[(size_t)irow * NROW + (j0 + wn * 64 + n * 16 + ocol)] = (unsigned char)key;
            }
        }
    }
}

// ---------------------------------------------------------------------------
// Kernel 3: per-row top-K on 7-bit keys, one wave per row.
// SWAR byte counting via v_sad_u8; dual binary search, 7 iterations;
// max side via complement counts/sums. (Verified round 5.)
// ---------------------------------------------------------------------------
__global__ __launch_bounds__(256) void select_kernel(const unsigned char* __restrict__ dist8,
                                                     float* __restrict__ loss, int r0) {
    const int tid  = threadIdx.x;
    const int lane = tid & 63;
    const int wid  = tid >> 6;
    const int rb   = blockIdx.x * 4 + wid;  // band-local row
    const int grow = r0 + rb;               // global row

    const uint4* __restrict__ P = (const uint4*)(dist8 + (size_t)rb * NROW);
    unsigned w[16];
#pragma unroll
    for (int i = 0; i < 4; ++i) {
        uint4 v = P[i * 64 + lane];
        w[4 * i + 0] = v.x; w[4 * i + 1] = v.y;
        w[4 * i + 2] = v.z; w[4 * i + 3] = v.w;
    }
    const unsigned dku = (unsigned)dist8[(size_t)rb * NROW + grow];  // diagonal key
    const unsigned M = 0x80808080u;
    const unsigned zero = 0u;

    // total row byte-sum (per lane), reduced later
    unsigned rs = 0;
#pragma unroll
    for (int i = 0; i < 16; ++i) rs = sad_u8(w[i], zero, rs);

    // ---- dual binary search over T in [0,128], 7 iterations ----
    int lo1 = 0, hi1 = 128, clo = 0;   // min side: largest T with cnt(<T) < K
    int lo2 = -1, hi2 = 127, chi = 0;  // max side: smallest T with cnt(>T) < K
#pragma unroll 1
    for (int it = 0; it < 7; ++it) {
        const int mid1 = (lo1 + hi1) >> 1;
        const int mid2 = (lo2 + hi2) >> 1;
        const unsigned C1 = (unsigned)(127 + mid1) * 0x01010101u;
        const unsigned C2 = (unsigned)(128 + mid2) * 0x01010101u;  // cntlt(mid2+1)
        unsigned a1 = 0, a2 = 0;
#pragma unroll
        for (int i = 0; i < 16; ++i) {
            a1 = sad_u8((C1 - w[i]) & M, zero, a1);
            a2 = sad_u8((C2 - w[i]) & M, zero, a2);
        }
        int cc = (int)((a1 >> 7) | ((a2 >> 7) << 16));
#pragma unroll
        for (int off = 32; off; off >>= 1) cc += __shfl_xor(cc, off, 64);
        cc = __builtin_amdgcn_readfirstlane(cc);
        const int c1 = (cc & 0xFFFF) - ((dku < (unsigned)mid1) ? 1 : 0);
        const int c2 = (4096 - (cc >> 16)) - (((int)dku > mid2) ? 1 : 0);
        if (c1 < KSEL) { lo1 = mid1; clo = c1; } else hi1 = mid1;
        if (c2 < KSEL) { hi2 = mid2; chi = c2; } else lo2 = mid2;
    }
    const int Tmin = lo1, Tmax = hi2;

    // ---- masked sums: sumlt(Tmin), sumlt(Tmax+1) ----
    const unsigned CA = (unsigned)(127 + Tmin) * 0x01010101u;
    const unsigned CB = (unsigned)(128 + Tmax) * 0x01010101u;
    unsigned sA = 0, sB = 0;
#pragma unroll
    for (int i = 0; i < 16; ++i) {
        const unsigned mA = ((CA - w[i]) & M) >> 7;
        sA = sad_u8(w[i] & ((mA << 8) - mA), zero, sA);
        const unsigned mB = ((CB - w[i]) & M) >> 7;
        sB = sad_u8(w[i] & ((mB << 8) - mB), zero, sB);
    }
#pragma unroll
    for (int off = 32; off; off >>= 1) {
        rs += __shfl_xor(rs, off, 64);
        sA += __shfl_xor(sA, off, 64);
        sB += __shfl_xor(sB, off, 64);
    }

    const int sum_min_i = (int)sA - ((dku < (unsigned)Tmin) ? (int)dku : 0)
                        + (KSEL - clo) * Tmin;
    const int sum_gt    = (int)(rs - sB);  // sum of keys > Tmax (incl diag)
    const int sum_max_i = sum_gt - (((int)dku > Tmax) ? (int)dku : 0)
                        + (KSEL - chi) * Tmax;

    if (lane == 0) {
        const float inv = 1.0f / 127.0f;
        const float total = (float)(sum_min_i + sum_max_i) * inv;
        const float dap = (float)dku * inv;
        const float neg = -0.0125f * total;  // -((1-prior)/(2K)) * sum
        const float pos = 0.5f * dap;        // prior * dist_ap
        loss[grow] = (neg < 0.f) ? -neg : (pos + neg);
    }
}

// ---------------------------------------------------------------------------
// Kernel 4: deterministic mean of loss[0..N-1] -> out[0]
// ---------------------------------------------------------------------------
__global__ __launch_bounds__(256) void finalize_kernel(const float* __restrict__ loss,
                                                       float* __restrict__ out) {
    const int tid = threadIdx.x;
    float s = 0.f;
    for (int k = tid; k < NROW; k += 256) s += loss[k];
#pragma unroll
    for (int off = 32; off; off >>= 1) s += __shfl_xor(s, off, 64);
    __shared__ float p[4];
    if ((tid & 63) == 0) p[tid >> 6] = s;
    __syncthreads();
    if (tid == 0) out[0] = (p[0] + p[1] + p[2] + p[3]) * (1.0f / (float)NROW);
}

// ---------------------------------------------------------------------------
extern "C" void kernel_launch(void* const* d_in, const int* in_sizes, int n_in,
                              void* d_out, int out_size, void* d_ws, size_t ws_size,
                              hipStream_t stream) {
    const float* A = (const float*)d_in[0];  // input  [N,C] f32
    const float* B = (const float*)d_in[1];  // target [N,C] f32

    char* ws = (char*)d_ws;
    const size_t norm_bytes = (size_t)NROW * CDIM * 2;        // 2 MB each
    ushort* An    = (ushort*)ws;
    ushort* Bn    = (ushort*)(ws + norm_bytes);
    float*  lossv = (float*)(ws + 2 * norm_bytes);            // 16 KB
    unsigned char* dist8 = (unsigned char*)(ws + 2 * norm_bytes + NROW * 4);
    const size_t fixed = 2 * norm_bytes + (size_t)NROW * 4;

    // band rows sized to fit ws (4 KB per row); floor at 128 (GEMM tile height)
    int band = NROW;
    while (band > 128 && fixed + (size_t)band * NROW > ws_size) band >>= 1;

    prep_kernel<<<2 * NROW / 4, 256, 0, stream>>>(A, B, An, Bn);
    for (int r0 = 0; r0 < NROW; r0 += band) {
        gemm16_kernel<<<dim3(NROW / 128, band / 128), 256, 0, stream>>>(An, Bn, dist8, r0);
        select_kernel<<<band / 4, 256, 0, stream>>>(dist8, lossv, r0);
    }
    finalize_kernel<<<1, 256, 0, stream>>>(lossv, (float*)d_out);
}